// Round 14
// baseline (184.616 us; speedup 1.0000x reference)
//
#include <hip/hip_runtime.h>
#include <math.h>

#define DD 2048
#define DTC 0.01f
#define NSTEPS 30

typedef float floatx4 __attribute__((ext_vector_type(4)));

__device__ __forceinline__ void lorenz_deriv(float x, float y, float z,
                                             float sigma, float rho, float beta,
                                             float& dx, float& dy, float& dz) {
    dx = sigma * (y - x);
    dy = x * (rho - z) - y;
    dz = x * y - beta * z;
}

__device__ __forceinline__ float fast_tanh(float p) {
    float e = __expf(2.0f * p);
    return 1.0f - __fdividef(2.0f, e + 1.0f);
}

// K_A (R10 version, measured ~20us = at HBM floor).
__global__ __launch_bounds__(256) void kA_state0(
    const float* __restrict__ x, const float* __restrict__ W_in,
    const float* __restrict__ b_in, float* __restrict__ state0,
    const float* __restrict__ W_out, float* __restrict__ wsT) {
    __shared__ float g_lds[4][16][13];
    const int tid = threadIdx.x;
    const int lane = tid & 63;
    const int wv = tid >> 6;
    const int row0 = blockIdx.x * 4;
    const int c0 = tid * 4;
    const int c1 = 1024 + tid * 4;

    floatx4 xr0[4], xr1[4];
#pragma unroll
    for (int r = 0; r < 4; ++r) {
        const float* p = x + (size_t)(row0 + r) * DD;
        xr0[r] = *reinterpret_cast<const floatx4*>(p + c0);
        xr1[r] = *reinterpret_cast<const floatx4*>(p + c1);
    }
    floatx4 w0[3], w1[3];
#pragma unroll
    for (int k = 0; k < 3; ++k) {
        const float* p = W_in + (size_t)k * DD;
        w0[k] = *reinterpret_cast<const floatx4*>(p + c0);
        w1[k] = *reinterpret_cast<const floatx4*>(p + c1);
    }

    float s[12];
#pragma unroll
    for (int r = 0; r < 4; ++r) {
#pragma unroll
        for (int k = 0; k < 3; ++k) {
            floatx4 t = xr0[r] * w0[k] + xr1[r] * w1[k];
            s[r * 3 + k] = (t.x + t.y) + (t.z + t.w);
        }
    }

#pragma unroll
    for (int o = 0; o < 12; ++o) {
        s[o] += __shfl_xor(s[o], 32, 64);
        s[o] += __shfl_xor(s[o], 16, 64);
    }
    if (lane < 16) {
#pragma unroll
        for (int o = 0; o < 12; ++o) g_lds[wv][lane][o] = s[o];
    }
    __syncthreads();

    if (tid < 192) {
        const int o = tid >> 4;
        const int j = tid & 15;
        float v = g_lds[0][j][o] + g_lds[1][j][o] + g_lds[2][j][o] + g_lds[3][j][o];
#pragma unroll
        for (int off = 1; off < 16; off <<= 1) v += __shfl_xor(v, off, 64);
        if (j == 0) {
            state0[(size_t)(row0 + o / 3) * 3 + (o % 3)] = v + b_in[o % 3];
        }
    }

    if (blockIdx.x < 144) {
        const int oidx = blockIdx.x * 256 + tid;
        const int k = oidx >> 11;
        const int c = oidx & 2047;
        wsT[oidx] = W_out[c * 18 + k];
    }
}

// K_B: one thread per row, all 64 lanes integrate concurrently.
__global__ __launch_bounds__(256) void kB_integrate(
    const float* __restrict__ state0, const float* __restrict__ lorenz,
    float* __restrict__ feats) {
    const int row = blockIdx.x * 256 + threadIdx.x;
    const float sigma = fmaxf(fabsf(lorenz[0]), 0.1f);
    const float rho   = fmaxf(fabsf(lorenz[1]), 0.1f);
    const float beta  = fmaxf(fabsf(lorenz[2]), 0.1f);

    float sx = state0[(size_t)row * 3 + 0];
    float sy = state0[(size_t)row * 3 + 1];
    float sz = state0[(size_t)row * 3 + 2];
    const float ix = sx, iy = sy, iz = sz;
    float sux = sx, suy = sy, suz = sz;
    float sqx = sx * sx, sqy = sy * sy, sqz = sz * sz;
    float mnx = sx, mny = sy, mnz = sz;
    float mxx = sx, mxy = sy, mxz = sz;
#pragma unroll 1
    for (int t = 0; t < NSTEPS; ++t) {
        float k1x, k1y, k1z, k2x, k2y, k2z, k3x, k3y, k3z, k4x, k4y, k4z;
        float ax, ay, az;
        lorenz_deriv(sx, sy, sz, sigma, rho, beta, k1x, k1y, k1z);
        ax = sx + 0.5f * DTC * k1x; ay = sy + 0.5f * DTC * k1y; az = sz + 0.5f * DTC * k1z;
        lorenz_deriv(ax, ay, az, sigma, rho, beta, k2x, k2y, k2z);
        ax = sx + 0.5f * DTC * k2x; ay = sy + 0.5f * DTC * k2y; az = sz + 0.5f * DTC * k2z;
        lorenz_deriv(ax, ay, az, sigma, rho, beta, k3x, k3y, k3z);
        ax = sx + DTC * k3x; ay = sy + DTC * k3y; az = sz + DTC * k3z;
        lorenz_deriv(ax, ay, az, sigma, rho, beta, k4x, k4y, k4z);
        sx += (DTC / 6.0f) * (k1x + 2.0f * k2x + 2.0f * k3x + k4x);
        sy += (DTC / 6.0f) * (k1y + 2.0f * k2y + 2.0f * k3y + k4y);
        sz += (DTC / 6.0f) * (k1z + 2.0f * k2z + 2.0f * k3z + k4z);
        sux += sx; suy += sy; suz += sz;
        sqx += sx * sx; sqy += sy * sy; sqz += sz * sz;
        mnx = fminf(mnx, sx); mny = fminf(mny, sy); mnz = fminf(mnz, sz);
        mxx = fmaxf(mxx, sx); mxy = fmaxf(mxy, sy); mxz = fmaxf(mxz, sz);
    }
    const float inv31 = 1.0f / 31.0f;
    const float inv30 = 1.0f / 30.0f;
    const float mex = sux * inv31, mey = suy * inv31, mez = suz * inv31;
    const float vax = fmaxf((sqx - sux * mex) * inv30, 0.0f);
    const float vay = fmaxf((sqy - suy * mey) * inv30, 0.0f);
    const float vaz = fmaxf((sqz - suz * mez) * inv30, 0.0f);
    float* f = feats + (size_t)row * 18;
    f[0]  = ix;  f[1]  = iy;  f[2]  = iz;
    f[3]  = sx;  f[4]  = sy;  f[5]  = sz;
    f[6]  = mex; f[7]  = mey; f[8]  = mez;
    f[9]  = sqrtf(vax); f[10] = sqrtf(vay); f[11] = sqrtf(vaz);
    f[12] = mnx; f[13] = mny; f[14] = mnz;
    f[15] = mxx; f[16] = mxy; f[17] = mxz;
}

// K_C v2: normal (cacheable) float4 stores instead of NT; feats LDS padded to
// 20 floats/row (16B-aligned rows) and copied to registers per row-pair so
// the compiler emits ds_read_b128s (10 DS ops/iter vs 36 scalar).
__global__ __launch_bounds__(256) void kC_out(
    const float* __restrict__ x, const float* __restrict__ feats,
    const float* __restrict__ wsT, const float* __restrict__ b_out,
    const float* __restrict__ strength, float* __restrict__ out) {
    __shared__ float f_lds[32][20];   // padded: rows 80B -> 16B aligned
    const int tid = threadIdx.x;
    const int row0 = blockIdx.x * 32;
    const int c0 = blockIdx.y * 1024 + tid * 4;

    {
        const float* src = feats + (size_t)row0 * 18;
#pragma unroll
        for (int i = 0; i < 3; ++i) {
            const int idx = tid + i * 256;
            if (idx < 576) f_lds[idx / 18][idx % 18] = src[idx];
        }
    }

    floatx4 wk[18];
#pragma unroll
    for (int k = 0; k < 18; ++k) {
        wk[k] = *reinterpret_cast<const floatx4*>(wsT + (size_t)k * DD + c0);
    }
    const floatx4 bo = *reinterpret_cast<const floatx4*>(b_out + c0);
    const float sabs = fabsf(strength[0]);
    __syncthreads();

#pragma unroll 1
    for (int r = 0; r < 32; r += 2) {
        const int rowA = row0 + r, rowB = row0 + r + 1;
        float fr0[18], fr1[18];
#pragma unroll
        for (int k = 0; k < 18; ++k) { fr0[k] = f_lds[r][k]; fr1[k] = f_lds[r + 1][k]; }
        const floatx4 xA = *reinterpret_cast<const floatx4*>(x + (size_t)rowA * DD + c0);
        const floatx4 xB = *reinterpret_cast<const floatx4*>(x + (size_t)rowB * DD + c0);
        floatx4 pA = bo, pB = bo;
#pragma unroll
        for (int k = 0; k < 18; ++k) {
            pA += fr0[k] * wk[k];
            pB += fr1[k] * wk[k];
        }
        floatx4 oA, oB;
        oA.x = xA.x + fast_tanh(pA.x) * sabs;
        oA.y = xA.y + fast_tanh(pA.y) * sabs;
        oA.z = xA.z + fast_tanh(pA.z) * sabs;
        oA.w = xA.w + fast_tanh(pA.w) * sabs;
        oB.x = xB.x + fast_tanh(pB.x) * sabs;
        oB.y = xB.y + fast_tanh(pB.y) * sabs;
        oB.z = xB.z + fast_tanh(pB.z) * sabs;
        oB.w = xB.w + fast_tanh(pB.w) * sabs;
        *reinterpret_cast<floatx4*>(out + (size_t)rowA * DD + c0) = oA;
        *reinterpret_cast<floatx4*>(out + (size_t)rowB * DD + c0) = oB;
    }
}

extern "C" void kernel_launch(void* const* d_in, const int* in_sizes, int n_in,
                              void* d_out, int out_size, void* d_ws, size_t ws_size,
                              hipStream_t stream) {
    const float* x        = (const float*)d_in[0];
    const float* lorenz   = (const float*)d_in[1];
    const float* strength = (const float*)d_in[2];
    const float* W_in     = (const float*)d_in[3];
    const float* b_in     = (const float*)d_in[4];
    const float* W_out    = (const float*)d_in[5];
    const float* b_out    = (const float*)d_in[6];
    float* out = (float*)d_out;

    const int N = in_sizes[0] / DD;  // 16384
    float* state0 = (float*)d_ws;            // N*3 floats
    float* feats  = state0 + (size_t)N * 3;  // N*18 floats
    float* wsT    = feats + (size_t)N * 18;  // 18*2048 floats

    kA_state0<<<N / 4, 256, 0, stream>>>(x, W_in, b_in, state0, W_out, wsT);
    kB_integrate<<<N / 256, 256, 0, stream>>>(state0, lorenz, feats);
    dim3 g3(N / 32, DD / 1024);
    // Timing probe: kC launched 3x (idempotent). Delta vs R10 = 2*(kC+gap).
    kC_out<<<g3, 256, 0, stream>>>(x, feats, wsT, b_out, strength, out);
    kC_out<<<g3, 256, 0, stream>>>(x, feats, wsT, b_out, strength, out);
    kC_out<<<g3, 256, 0, stream>>>(x, feats, wsT, b_out, strength, out);
}

// Round 15
// 89.967 us; speedup vs baseline: 2.0520x; 2.0520x over previous
//
#include <hip/hip_runtime.h>
#include <math.h>

#define DD 2048
#define DTC 0.01f
#define NSTEPS 30

typedef float floatx4 __attribute__((ext_vector_type(4)));

__device__ __forceinline__ void lorenz_deriv(float x, float y, float z,
                                             float sigma, float rho, float beta,
                                             float& dx, float& dy, float& dz) {
    dx = sigma * (y - x);
    dy = x * (rho - z) - y;
    dz = x * y - beta * z;
}

__device__ __forceinline__ float fast_tanh(float p) {
    float e = __expf(2.0f * p);
    return 1.0f - __fdividef(2.0f, e + 1.0f);
}

// K_AB: state0 + integrate fused. 4 rows/block, 256 threads.
// Stream x (packed 1KB wave-loads) -> butterfly+LDS reduce -> lanes 0..3
// integrate the block's 4 rows and write feats directly.
// Side job: blocks 0..143 transpose W_out -> wsT.
__global__ __launch_bounds__(256, 4) void kAB(
    const float* __restrict__ x, const float* __restrict__ W_in,
    const float* __restrict__ b_in, const float* __restrict__ lorenz,
    float* __restrict__ feats,
    const float* __restrict__ W_out, float* __restrict__ wsT) {
    __shared__ float g_lds[4][16][13];
    __shared__ float st0[12];
    const int tid = threadIdx.x;
    const int lane = tid & 63;
    const int wv = tid >> 6;
    const int row0 = blockIdx.x * 4;
    const int c0 = tid * 4;
    const int c1 = 1024 + tid * 4;

    floatx4 xr0[4], xr1[4];
#pragma unroll
    for (int r = 0; r < 4; ++r) {
        const float* p = x + (size_t)(row0 + r) * DD;
        xr0[r] = *reinterpret_cast<const floatx4*>(p + c0);
        xr1[r] = *reinterpret_cast<const floatx4*>(p + c1);
    }
    floatx4 w0[3], w1[3];
#pragma unroll
    for (int k = 0; k < 3; ++k) {
        const float* p = W_in + (size_t)k * DD;
        w0[k] = *reinterpret_cast<const floatx4*>(p + c0);
        w1[k] = *reinterpret_cast<const floatx4*>(p + c1);
    }

    // W_out transpose side job (overlaps streaming on other blocks).
    if (blockIdx.x < 144) {
        const int oidx = blockIdx.x * 256 + tid;
        const int k = oidx >> 11;
        const int c = oidx & 2047;
        wsT[oidx] = W_out[c * 18 + k];
    }

    float s[12];
#pragma unroll
    for (int r = 0; r < 4; ++r) {
#pragma unroll
        for (int k = 0; k < 3; ++k) {
            floatx4 t = xr0[r] * w0[k] + xr1[r] * w1[k];
            s[r * 3 + k] = (t.x + t.y) + (t.z + t.w);
        }
    }

#pragma unroll
    for (int o = 0; o < 12; ++o) {
        s[o] += __shfl_xor(s[o], 32, 64);
        s[o] += __shfl_xor(s[o], 16, 64);
    }
    if (lane < 16) {
#pragma unroll
        for (int o = 0; o < 12; ++o) g_lds[wv][lane][o] = s[o];
    }
    __syncthreads();

    if (tid < 192) {
        const int o = tid >> 4;
        const int j = tid & 15;
        float v = g_lds[0][j][o] + g_lds[1][j][o] + g_lds[2][j][o] + g_lds[3][j][o];
#pragma unroll
        for (int off = 1; off < 16; off <<= 1) v += __shfl_xor(v, off, 64);
        if (j == 0) st0[o] = v + b_in[o % 3];
    }
    __syncthreads();

    // Lanes 0..3 of wave 0 integrate the block's 4 rows.
    if (tid < 4) {
        const float sigma = fmaxf(fabsf(lorenz[0]), 0.1f);
        const float rho   = fmaxf(fabsf(lorenz[1]), 0.1f);
        const float beta  = fmaxf(fabsf(lorenz[2]), 0.1f);
        float sx = st0[tid * 3 + 0];
        float sy = st0[tid * 3 + 1];
        float sz = st0[tid * 3 + 2];
        const float ix = sx, iy = sy, iz = sz;
        float sux = sx, suy = sy, suz = sz;
        float sqx = sx * sx, sqy = sy * sy, sqz = sz * sz;
        float mnx = sx, mny = sy, mnz = sz;
        float mxx = sx, mxy = sy, mxz = sz;
#pragma unroll 1
        for (int t = 0; t < NSTEPS; ++t) {
            float k1x, k1y, k1z, k2x, k2y, k2z, k3x, k3y, k3z, k4x, k4y, k4z;
            float ax, ay, az;
            lorenz_deriv(sx, sy, sz, sigma, rho, beta, k1x, k1y, k1z);
            ax = sx + 0.5f * DTC * k1x; ay = sy + 0.5f * DTC * k1y; az = sz + 0.5f * DTC * k1z;
            lorenz_deriv(ax, ay, az, sigma, rho, beta, k2x, k2y, k2z);
            ax = sx + 0.5f * DTC * k2x; ay = sy + 0.5f * DTC * k2y; az = sz + 0.5f * DTC * k2z;
            lorenz_deriv(ax, ay, az, sigma, rho, beta, k3x, k3y, k3z);
            ax = sx + DTC * k3x; ay = sy + DTC * k3y; az = sz + DTC * k3z;
            lorenz_deriv(ax, ay, az, sigma, rho, beta, k4x, k4y, k4z);
            sx += (DTC / 6.0f) * (k1x + 2.0f * k2x + 2.0f * k3x + k4x);
            sy += (DTC / 6.0f) * (k1y + 2.0f * k2y + 2.0f * k3y + k4y);
            sz += (DTC / 6.0f) * (k1z + 2.0f * k2z + 2.0f * k3z + k4z);
            sux += sx; suy += sy; suz += sz;
            sqx += sx * sx; sqy += sy * sy; sqz += sz * sz;
            mnx = fminf(mnx, sx); mny = fminf(mny, sy); mnz = fminf(mnz, sz);
            mxx = fmaxf(mxx, sx); mxy = fmaxf(mxy, sy); mxz = fmaxf(mxz, sz);
        }
        const float inv31 = 1.0f / 31.0f;
        const float inv30 = 1.0f / 30.0f;
        const float mex = sux * inv31, mey = suy * inv31, mez = suz * inv31;
        const float vax = fmaxf((sqx - sux * mex) * inv30, 0.0f);
        const float vay = fmaxf((sqy - suy * mey) * inv30, 0.0f);
        const float vaz = fmaxf((sqz - suz * mez) * inv30, 0.0f);
        float* f = feats + (size_t)(row0 + tid) * 18;
        f[0]  = ix;  f[1]  = iy;  f[2]  = iz;
        f[3]  = sx;  f[4]  = sy;  f[5]  = sz;
        f[6]  = mex; f[7]  = mey; f[8]  = mez;
        f[9]  = sqrtf(vax); f[10] = sqrtf(vay); f[11] = sqrtf(vaz);
        f[12] = mnx; f[13] = mny; f[14] = mnz;
        f[15] = mxx; f[16] = mxy; f[17] = mxz;
    }
}

// K_C: 32 rows x 1024 cols per block; 4-row batches (4 loads -> compute ->
// 4 stores) to reduce HBM read/write turnarounds. Coalesced transposed
// weights; feats from padded LDS.
__global__ __launch_bounds__(256) void kC_out(
    const float* __restrict__ x, const float* __restrict__ feats,
    const float* __restrict__ wsT, const float* __restrict__ b_out,
    const float* __restrict__ strength, float* __restrict__ out) {
    __shared__ float f_lds[32][20];
    const int tid = threadIdx.x;
    const int row0 = blockIdx.x * 32;
    const int c0 = blockIdx.y * 1024 + tid * 4;

    {
        const float* src = feats + (size_t)row0 * 18;
#pragma unroll
        for (int i = 0; i < 3; ++i) {
            const int idx = tid + i * 256;
            if (idx < 576) f_lds[idx / 18][idx % 18] = src[idx];
        }
    }

    floatx4 wk[18];
#pragma unroll
    for (int k = 0; k < 18; ++k) {
        wk[k] = *reinterpret_cast<const floatx4*>(wsT + (size_t)k * DD + c0);
    }
    const floatx4 bo = *reinterpret_cast<const floatx4*>(b_out + c0);
    const float sabs = fabsf(strength[0]);
    __syncthreads();

#pragma unroll 1
    for (int r = 0; r < 32; r += 4) {
        floatx4 xv[4];
#pragma unroll
        for (int q = 0; q < 4; ++q) {
            xv[q] = *reinterpret_cast<const floatx4*>(x + (size_t)(row0 + r + q) * DD + c0);
        }
        floatx4 p[4];
#pragma unroll
        for (int q = 0; q < 4; ++q) {
            p[q] = bo;
            const float* f = &f_lds[r + q][0];
#pragma unroll
            for (int k = 0; k < 18; ++k) p[q] += f[k] * wk[k];
        }
#pragma unroll
        for (int q = 0; q < 4; ++q) {
            floatx4 o;
            o.x = xv[q].x + fast_tanh(p[q].x) * sabs;
            o.y = xv[q].y + fast_tanh(p[q].y) * sabs;
            o.z = xv[q].z + fast_tanh(p[q].z) * sabs;
            o.w = xv[q].w + fast_tanh(p[q].w) * sabs;
            *reinterpret_cast<floatx4*>(out + (size_t)(row0 + r + q) * DD + c0) = o;
        }
    }
}

extern "C" void kernel_launch(void* const* d_in, const int* in_sizes, int n_in,
                              void* d_out, int out_size, void* d_ws, size_t ws_size,
                              hipStream_t stream) {
    const float* x        = (const float*)d_in[0];
    const float* lorenz   = (const float*)d_in[1];
    const float* strength = (const float*)d_in[2];
    const float* W_in     = (const float*)d_in[3];
    const float* b_in     = (const float*)d_in[4];
    const float* W_out    = (const float*)d_in[5];
    const float* b_out    = (const float*)d_in[6];
    float* out = (float*)d_out;

    const int N = in_sizes[0] / DD;  // 16384
    float* feats = (float*)d_ws;             // N*18 floats
    float* wsT   = feats + (size_t)N * 18;   // 18*2048 floats

    kAB<<<N / 4, 256, 0, stream>>>(x, W_in, b_in, lorenz, feats, W_out, wsT);
    dim3 g3(N / 32, DD / 1024);
    kC_out<<<g3, 256, 0, stream>>>(x, feats, wsT, b_out, strength, out);
}

// Round 16
// 77.591 us; speedup vs baseline: 2.3794x; 1.1595x over previous
//
#include <hip/hip_runtime.h>
#include <math.h>

#define DD 2048
#define DTC 0.01f
#define NSTEPS 30

typedef float floatx4 __attribute__((ext_vector_type(4)));

__device__ __forceinline__ void lorenz_deriv(float x, float y, float z,
                                             float sigma, float rho, float beta,
                                             float& dx, float& dy, float& dz) {
    dx = sigma * (y - x);
    dy = x * (rho - z) - y;
    dz = x * y - beta * z;
}

__device__ __forceinline__ float fast_tanh(float p) {
    float e = __expf(2.0f * p);
    return 1.0f - __fdividef(2.0f, e + 1.0f);
}

// K_A: state0 = x @ W_in^T + b_in. 4 rows/block, 256 threads. Thread owns
// cols {4t..4t+3} and {1024+4t..4t+3+1024}: every wave-load is a packed 1KB
// segment. Butterfly+LDS reduce. Side job: blocks 0..143 transpose W_out.
// Measured ~20us = at the HBM-read floor (R12 probe).
__global__ __launch_bounds__(256) void kA_state0(
    const float* __restrict__ x, const float* __restrict__ W_in,
    const float* __restrict__ b_in, float* __restrict__ state0,
    const float* __restrict__ W_out, float* __restrict__ wsT) {
    __shared__ float g_lds[4][16][13];
    const int tid = threadIdx.x;
    const int lane = tid & 63;
    const int wv = tid >> 6;
    const int row0 = blockIdx.x * 4;
    const int c0 = tid * 4;
    const int c1 = 1024 + tid * 4;

    floatx4 xr0[4], xr1[4];
#pragma unroll
    for (int r = 0; r < 4; ++r) {
        const float* p = x + (size_t)(row0 + r) * DD;
        xr0[r] = *reinterpret_cast<const floatx4*>(p + c0);
        xr1[r] = *reinterpret_cast<const floatx4*>(p + c1);
    }
    floatx4 w0[3], w1[3];
#pragma unroll
    for (int k = 0; k < 3; ++k) {
        const float* p = W_in + (size_t)k * DD;
        w0[k] = *reinterpret_cast<const floatx4*>(p + c0);
        w1[k] = *reinterpret_cast<const floatx4*>(p + c1);
    }

    float s[12];
#pragma unroll
    for (int r = 0; r < 4; ++r) {
#pragma unroll
        for (int k = 0; k < 3; ++k) {
            floatx4 t = xr0[r] * w0[k] + xr1[r] * w1[k];
            s[r * 3 + k] = (t.x + t.y) + (t.z + t.w);
        }
    }

#pragma unroll
    for (int o = 0; o < 12; ++o) {
        s[o] += __shfl_xor(s[o], 32, 64);
        s[o] += __shfl_xor(s[o], 16, 64);
    }
    if (lane < 16) {
#pragma unroll
        for (int o = 0; o < 12; ++o) g_lds[wv][lane][o] = s[o];
    }
    __syncthreads();

    if (tid < 192) {
        const int o = tid >> 4;
        const int j = tid & 15;
        float v = g_lds[0][j][o] + g_lds[1][j][o] + g_lds[2][j][o] + g_lds[3][j][o];
#pragma unroll
        for (int off = 1; off < 16; off <<= 1) v += __shfl_xor(v, off, 64);
        if (j == 0) {
            state0[(size_t)(row0 + o / 3) * 3 + (o % 3)] = v + b_in[o % 3];
        }
    }

    if (blockIdx.x < 144) {
        const int oidx = blockIdx.x * 256 + tid;
        const int k = oidx >> 11;
        const int c = oidx & 2047;
        wsT[oidx] = W_out[c * 18 + k];
    }
}

// K_B: one thread per row, all 64 lanes integrate concurrently (~4us).
__global__ __launch_bounds__(256) void kB_integrate(
    const float* __restrict__ state0, const float* __restrict__ lorenz,
    float* __restrict__ feats) {
    const int row = blockIdx.x * 256 + threadIdx.x;
    const float sigma = fmaxf(fabsf(lorenz[0]), 0.1f);
    const float rho   = fmaxf(fabsf(lorenz[1]), 0.1f);
    const float beta  = fmaxf(fabsf(lorenz[2]), 0.1f);

    float sx = state0[(size_t)row * 3 + 0];
    float sy = state0[(size_t)row * 3 + 1];
    float sz = state0[(size_t)row * 3 + 2];
    const float ix = sx, iy = sy, iz = sz;
    float sux = sx, suy = sy, suz = sz;
    float sqx = sx * sx, sqy = sy * sy, sqz = sz * sz;
    float mnx = sx, mny = sy, mnz = sz;
    float mxx = sx, mxy = sy, mxz = sz;
#pragma unroll 1
    for (int t = 0; t < NSTEPS; ++t) {
        float k1x, k1y, k1z, k2x, k2y, k2z, k3x, k3y, k3z, k4x, k4y, k4z;
        float ax, ay, az;
        lorenz_deriv(sx, sy, sz, sigma, rho, beta, k1x, k1y, k1z);
        ax = sx + 0.5f * DTC * k1x; ay = sy + 0.5f * DTC * k1y; az = sz + 0.5f * DTC * k1z;
        lorenz_deriv(ax, ay, az, sigma, rho, beta, k2x, k2y, k2z);
        ax = sx + 0.5f * DTC * k2x; ay = sy + 0.5f * DTC * k2y; az = sz + 0.5f * DTC * k2z;
        lorenz_deriv(ax, ay, az, sigma, rho, beta, k3x, k3y, k3z);
        ax = sx + DTC * k3x; ay = sy + DTC * k3y; az = sz + DTC * k3z;
        lorenz_deriv(ax, ay, az, sigma, rho, beta, k4x, k4y, k4z);
        sx += (DTC / 6.0f) * (k1x + 2.0f * k2x + 2.0f * k3x + k4x);
        sy += (DTC / 6.0f) * (k1y + 2.0f * k2y + 2.0f * k3y + k4y);
        sz += (DTC / 6.0f) * (k1z + 2.0f * k2z + 2.0f * k3z + k4z);
        sux += sx; suy += sy; suz += sz;
        sqx += sx * sx; sqy += sy * sy; sqz += sz * sz;
        mnx = fminf(mnx, sx); mny = fminf(mny, sy); mnz = fminf(mnz, sz);
        mxx = fmaxf(mxx, sx); mxy = fmaxf(mxy, sy); mxz = fmaxf(mxz, sz);
    }
    const float inv31 = 1.0f / 31.0f;
    const float inv30 = 1.0f / 30.0f;
    const float mex = sux * inv31, mey = suy * inv31, mez = suz * inv31;
    const float vax = fmaxf((sqx - sux * mex) * inv30, 0.0f);
    const float vay = fmaxf((sqy - suy * mey) * inv30, 0.0f);
    const float vaz = fmaxf((sqz - suz * mez) * inv30, 0.0f);
    float* f = feats + (size_t)row * 18;
    f[0]  = ix;  f[1]  = iy;  f[2]  = iz;
    f[3]  = sx;  f[4]  = sy;  f[5]  = sz;
    f[6]  = mex; f[7]  = mey; f[8]  = mez;
    f[9]  = sqrtf(vax); f[10] = sqrtf(vay); f[11] = sqrtf(vaz);
    f[12] = mnx; f[13] = mny; f[14] = mnz;
    f[15] = mxx; f[16] = mxy; f[17] = mxz;
}

// K_C: 32 rows x 1024 cols per block (256 threads, 4 cols/thread).
// Coalesced transposed weights; feats tile in LDS; float4 x; NT stores.
// Measured ~50us = 5.4 TB/s mixed r/w stream (~86% of copy ceiling).
__global__ __launch_bounds__(256) void kC_out(
    const float* __restrict__ x, const float* __restrict__ feats,
    const float* __restrict__ wsT, const float* __restrict__ b_out,
    const float* __restrict__ strength, float* __restrict__ out) {
    __shared__ float f_lds[32 * 18];
    const int tid = threadIdx.x;
    const int row0 = blockIdx.x * 32;
    const int c0 = blockIdx.y * 1024 + tid * 4;

    {
        const float* src = feats + (size_t)row0 * 18;
        f_lds[tid] = src[tid];
        f_lds[tid + 256] = src[tid + 256];
        if (tid < 64) f_lds[tid + 512] = src[tid + 512];
    }

    floatx4 wk[18];
#pragma unroll
    for (int k = 0; k < 18; ++k) {
        wk[k] = *reinterpret_cast<const floatx4*>(wsT + (size_t)k * DD + c0);
    }
    const floatx4 bo = *reinterpret_cast<const floatx4*>(b_out + c0);
    const float sabs = fabsf(strength[0]);
    __syncthreads();

#pragma unroll 1
    for (int r = 0; r < 32; r += 2) {
        const int rowA = row0 + r, rowB = row0 + r + 1;
        const float* fA = f_lds + r * 18;
        const float* fB = f_lds + (r + 1) * 18;
        const floatx4 xA = *reinterpret_cast<const floatx4*>(x + (size_t)rowA * DD + c0);
        const floatx4 xB = *reinterpret_cast<const floatx4*>(x + (size_t)rowB * DD + c0);
        floatx4 pA = bo, pB = bo;
#pragma unroll
        for (int k = 0; k < 18; ++k) {
            pA += fA[k] * wk[k];
            pB += fB[k] * wk[k];
        }
        floatx4 oA, oB;
        oA.x = xA.x + fast_tanh(pA.x) * sabs;
        oA.y = xA.y + fast_tanh(pA.y) * sabs;
        oA.z = xA.z + fast_tanh(pA.z) * sabs;
        oA.w = xA.w + fast_tanh(pA.w) * sabs;
        oB.x = xB.x + fast_tanh(pB.x) * sabs;
        oB.y = xB.y + fast_tanh(pB.y) * sabs;
        oB.z = xB.z + fast_tanh(pB.z) * sabs;
        oB.w = xB.w + fast_tanh(pB.w) * sabs;
        __builtin_nontemporal_store(oA, reinterpret_cast<floatx4*>(out + (size_t)rowA * DD + c0));
        __builtin_nontemporal_store(oB, reinterpret_cast<floatx4*>(out + (size_t)rowB * DD + c0));
    }
}

extern "C" void kernel_launch(void* const* d_in, const int* in_sizes, int n_in,
                              void* d_out, int out_size, void* d_ws, size_t ws_size,
                              hipStream_t stream) {
    const float* x        = (const float*)d_in[0];
    const float* lorenz   = (const float*)d_in[1];
    const float* strength = (const float*)d_in[2];
    const float* W_in     = (const float*)d_in[3];
    const float* b_in     = (const float*)d_in[4];
    const float* W_out    = (const float*)d_in[5];
    const float* b_out    = (const float*)d_in[6];
    float* out = (float*)d_out;

    const int N = in_sizes[0] / DD;  // 16384
    float* state0 = (float*)d_ws;            // N*3 floats
    float* feats  = state0 + (size_t)N * 3;  // N*18 floats
    float* wsT    = feats + (size_t)N * 18;  // 18*2048 floats

    kA_state0<<<N / 4, 256, 0, stream>>>(x, W_in, b_in, state0, W_out, wsT);
    kB_integrate<<<N / 256, 256, 0, stream>>>(state0, lorenz, feats);
    dim3 g3(N / 32, DD / 1024);
    kC_out<<<g3, 256, 0, stream>>>(x, feats, wsT, b_out, strength, out);
}

// Round 17
// 76.513 us; speedup vs baseline: 2.4129x; 1.0141x over previous
//
#include <hip/hip_runtime.h>
#include <math.h>

#define DD 2048
#define DTC 0.01f
#define NSTEPS 30

typedef float floatx4 __attribute__((ext_vector_type(4)));

__device__ __forceinline__ void lorenz_deriv(float x, float y, float z,
                                             float sigma, float rho, float beta,
                                             float& dx, float& dy, float& dz) {
    dx = sigma * (y - x);
    dy = x * (rho - z) - y;
    dz = x * y - beta * z;
}

__device__ __forceinline__ float fast_tanh(float p) {
    float e = __expf(2.0f * p);
    return 1.0f - __fdividef(2.0f, e + 1.0f);
}

// K_A: state0 = x @ W_in^T + b_in. 4 rows/block, 256 threads, packed 1KB
// wave-loads, butterfly+LDS reduce. Measured ~20us = 6.7 TB/s read stream
// (at the practical ceiling). Side job: blocks 0..143 transpose W_out.
__global__ __launch_bounds__(256) void kA_state0(
    const float* __restrict__ x, const float* __restrict__ W_in,
    const float* __restrict__ b_in, float* __restrict__ state0,
    const float* __restrict__ W_out, float* __restrict__ wsT) {
    __shared__ float g_lds[4][16][13];
    const int tid = threadIdx.x;
    const int lane = tid & 63;
    const int wv = tid >> 6;
    const int row0 = blockIdx.x * 4;
    const int c0 = tid * 4;
    const int c1 = 1024 + tid * 4;

    floatx4 xr0[4], xr1[4];
#pragma unroll
    for (int r = 0; r < 4; ++r) {
        const float* p = x + (size_t)(row0 + r) * DD;
        xr0[r] = *reinterpret_cast<const floatx4*>(p + c0);
        xr1[r] = *reinterpret_cast<const floatx4*>(p + c1);
    }
    floatx4 w0[3], w1[3];
#pragma unroll
    for (int k = 0; k < 3; ++k) {
        const float* p = W_in + (size_t)k * DD;
        w0[k] = *reinterpret_cast<const floatx4*>(p + c0);
        w1[k] = *reinterpret_cast<const floatx4*>(p + c1);
    }

    float s[12];
#pragma unroll
    for (int r = 0; r < 4; ++r) {
#pragma unroll
        for (int k = 0; k < 3; ++k) {
            floatx4 t = xr0[r] * w0[k] + xr1[r] * w1[k];
            s[r * 3 + k] = (t.x + t.y) + (t.z + t.w);
        }
    }

#pragma unroll
    for (int o = 0; o < 12; ++o) {
        s[o] += __shfl_xor(s[o], 32, 64);
        s[o] += __shfl_xor(s[o], 16, 64);
    }
    if (lane < 16) {
#pragma unroll
        for (int o = 0; o < 12; ++o) g_lds[wv][lane][o] = s[o];
    }
    __syncthreads();

    if (tid < 192) {
        const int o = tid >> 4;
        const int j = tid & 15;
        float v = g_lds[0][j][o] + g_lds[1][j][o] + g_lds[2][j][o] + g_lds[3][j][o];
#pragma unroll
        for (int off = 1; off < 16; off <<= 1) v += __shfl_xor(v, off, 64);
        if (j == 0) {
            state0[(size_t)(row0 + o / 3) * 3 + (o % 3)] = v + b_in[o % 3];
        }
    }

    if (blockIdx.x < 144) {
        const int oidx = blockIdx.x * 256 + tid;
        const int k = oidx >> 11;
        const int c = oidx & 2047;
        wsT[oidx] = W_out[c * 18 + k];
    }
}

// K_B: one thread per row, all 64 lanes integrate concurrently (~4us).
__global__ __launch_bounds__(256) void kB_integrate(
    const float* __restrict__ state0, const float* __restrict__ lorenz,
    float* __restrict__ feats) {
    const int row = blockIdx.x * 256 + threadIdx.x;
    const float sigma = fmaxf(fabsf(lorenz[0]), 0.1f);
    const float rho   = fmaxf(fabsf(lorenz[1]), 0.1f);
    const float beta  = fmaxf(fabsf(lorenz[2]), 0.1f);

    float sx = state0[(size_t)row * 3 + 0];
    float sy = state0[(size_t)row * 3 + 1];
    float sz = state0[(size_t)row * 3 + 2];
    const float ix = sx, iy = sy, iz = sz;
    float sux = sx, suy = sy, suz = sz;
    float sqx = sx * sx, sqy = sy * sy, sqz = sz * sz;
    float mnx = sx, mny = sy, mnz = sz;
    float mxx = sx, mxy = sy, mxz = sz;
#pragma unroll 1
    for (int t = 0; t < NSTEPS; ++t) {
        float k1x, k1y, k1z, k2x, k2y, k2z, k3x, k3y, k3z, k4x, k4y, k4z;
        float ax, ay, az;
        lorenz_deriv(sx, sy, sz, sigma, rho, beta, k1x, k1y, k1z);
        ax = sx + 0.5f * DTC * k1x; ay = sy + 0.5f * DTC * k1y; az = sz + 0.5f * DTC * k1z;
        lorenz_deriv(ax, ay, az, sigma, rho, beta, k2x, k2y, k2z);
        ax = sx + 0.5f * DTC * k2x; ay = sy + 0.5f * DTC * k2y; az = sz + 0.5f * DTC * k2z;
        lorenz_deriv(ax, ay, az, sigma, rho, beta, k3x, k3y, k3z);
        ax = sx + DTC * k3x; ay = sy + DTC * k3y; az = sz + DTC * k3z;
        lorenz_deriv(ax, ay, az, sigma, rho, beta, k4x, k4y, k4z);
        sx += (DTC / 6.0f) * (k1x + 2.0f * k2x + 2.0f * k3x + k4x);
        sy += (DTC / 6.0f) * (k1y + 2.0f * k2y + 2.0f * k3y + k4y);
        sz += (DTC / 6.0f) * (k1z + 2.0f * k2z + 2.0f * k3z + k4z);
        sux += sx; suy += sy; suz += sz;
        sqx += sx * sx; sqy += sy * sy; sqz += sz * sz;
        mnx = fminf(mnx, sx); mny = fminf(mny, sy); mnz = fminf(mnz, sz);
        mxx = fmaxf(mxx, sx); mxy = fmaxf(mxy, sy); mxz = fmaxf(mxz, sz);
    }
    const float inv31 = 1.0f / 31.0f;
    const float inv30 = 1.0f / 30.0f;
    const float mex = sux * inv31, mey = suy * inv31, mez = suz * inv31;
    const float vax = fmaxf((sqx - sux * mex) * inv30, 0.0f);
    const float vay = fmaxf((sqy - suy * mey) * inv30, 0.0f);
    const float vaz = fmaxf((sqz - suz * mez) * inv30, 0.0f);
    float* f = feats + (size_t)row * 18;
    f[0]  = ix;  f[1]  = iy;  f[2]  = iz;
    f[3]  = sx;  f[4]  = sy;  f[5]  = sz;
    f[6]  = mex; f[7]  = mey; f[8]  = mez;
    f[9]  = sqrtf(vax); f[10] = sqrtf(vay); f[11] = sqrtf(vaz);
    f[12] = mnx; f[13] = mny; f[14] = mnz;
    f[15] = mxx; f[16] = mxy; f[17] = mxz;
}

// K_C: 16 rows x 1024 cols per block (2048 blocks = 8/CU, doubled store-
// stream concurrency vs 32-row/4-per-CU). Coalesced transposed weights;
// feats tile in LDS; float4 x; NT stores.
__global__ __launch_bounds__(256) void kC_out(
    const float* __restrict__ x, const float* __restrict__ feats,
    const float* __restrict__ wsT, const float* __restrict__ b_out,
    const float* __restrict__ strength, float* __restrict__ out) {
    __shared__ float f_lds[16 * 18];   // 288 floats
    const int tid = threadIdx.x;
    const int row0 = blockIdx.x * 16;
    const int c0 = blockIdx.y * 1024 + tid * 4;

    {
        const float* src = feats + (size_t)row0 * 18;
        if (tid < 256) f_lds[tid] = src[tid];
        if (tid < 32) f_lds[tid + 256] = src[tid + 256];
    }

    floatx4 wk[18];
#pragma unroll
    for (int k = 0; k < 18; ++k) {
        wk[k] = *reinterpret_cast<const floatx4*>(wsT + (size_t)k * DD + c0);
    }
    const floatx4 bo = *reinterpret_cast<const floatx4*>(b_out + c0);
    const float sabs = fabsf(strength[0]);
    __syncthreads();

#pragma unroll 1
    for (int r = 0; r < 16; r += 2) {
        const int rowA = row0 + r, rowB = row0 + r + 1;
        const float* fA = f_lds + r * 18;
        const float* fB = f_lds + (r + 1) * 18;
        const floatx4 xA = *reinterpret_cast<const floatx4*>(x + (size_t)rowA * DD + c0);
        const floatx4 xB = *reinterpret_cast<const floatx4*>(x + (size_t)rowB * DD + c0);
        floatx4 pA = bo, pB = bo;
#pragma unroll
        for (int k = 0; k < 18; ++k) {
            pA += fA[k] * wk[k];
            pB += fB[k] * wk[k];
        }
        floatx4 oA, oB;
        oA.x = xA.x + fast_tanh(pA.x) * sabs;
        oA.y = xA.y + fast_tanh(pA.y) * sabs;
        oA.z = xA.z + fast_tanh(pA.z) * sabs;
        oA.w = xA.w + fast_tanh(pA.w) * sabs;
        oB.x = xB.x + fast_tanh(pB.x) * sabs;
        oB.y = xB.y + fast_tanh(pB.y) * sabs;
        oB.z = xB.z + fast_tanh(pB.z) * sabs;
        oB.w = xB.w + fast_tanh(pB.w) * sabs;
        __builtin_nontemporal_store(oA, reinterpret_cast<floatx4*>(out + (size_t)rowA * DD + c0));
        __builtin_nontemporal_store(oB, reinterpret_cast<floatx4*>(out + (size_t)rowB * DD + c0));
    }
}

extern "C" void kernel_launch(void* const* d_in, const int* in_sizes, int n_in,
                              void* d_out, int out_size, void* d_ws, size_t ws_size,
                              hipStream_t stream) {
    const float* x        = (const float*)d_in[0];
    const float* lorenz   = (const float*)d_in[1];
    const float* strength = (const float*)d_in[2];
    const float* W_in     = (const float*)d_in[3];
    const float* b_in     = (const float*)d_in[4];
    const float* W_out    = (const float*)d_in[5];
    const float* b_out    = (const float*)d_in[6];
    float* out = (float*)d_out;

    const int N = in_sizes[0] / DD;  // 16384
    float* state0 = (float*)d_ws;            // N*3 floats
    float* feats  = state0 + (size_t)N * 3;  // N*18 floats
    float* wsT    = feats + (size_t)N * 18;  // 18*2048 floats

    kA_state0<<<N / 4, 256, 0, stream>>>(x, W_in, b_in, state0, W_out, wsT);
    kB_integrate<<<N / 256, 256, 0, stream>>>(state0, lorenz, feats);
    dim3 g3(N / 16, DD / 1024);
    kC_out<<<g3, 256, 0, stream>>>(x, feats, wsT, b_out, strength, out);
}